// Round 7
// baseline (146.462 us; speedup 1.0000x reference)
//
#include <hip/hip_runtime.h>
#include <math.h>

// ---------------------------------------------------------------------------
// IrrepsToHessian, round 7.
//
// R6 post-mortem: top-5 = five 42us harness fills (0xAA poison of the 256MiB
// d_ws) -- all our kernels now < 41.4us. ~46us/iter of harness reset traffic
// is a fixed floor; our kernels+gaps ~95us vs ~35us theory -> overhead in
// extra launches and cart's 4096 one-wave blocks.
//
// R7: (1) single merged init kernel (1 block, 1024 thr) -- one launch fewer,
// no Cr round-trip. (2) cart: 256-thr blocks, wave-per-row-block, Mq pointer
// forced uniform with readfirstlane -> s_load survives the 4-wave shape
// (R5's failure mode, fixed properly). Grid 1024 matches mq's grid for
// XCD-local L2 reuse. (3) mq, sym_tiled unchanged.
// ---------------------------------------------------------------------------

#define NPATH 15

__constant__ int cP_L1[NPATH]   = {0,1,2,0,1,1,1,2,2,0,2,1,1,2,2};
__constant__ int cP_L2[NPATH]   = {0,1,2,1,0,1,2,1,2,2,0,1,2,1,2};
__constant__ int cP_LO[NPATH]   = {0,0,0,1,1,1,1,1,1,2,2,2,2,2,2};
// dense w3j concat offsets, sizes (2l1+1)(2l2+1)(2lo+1) -> total 615
__constant__ int cP_WOFF[NPATH] = {0,1,10,35,44,53,80,125,170,245,270,295,340,415,490};
// wq row offsets: cumsum of d1*d2 -> 189 rows total
__constant__ int cP_PROW[NPATH] = {0,1,10,35,38,41,50,65,80,105,110,115,124,139,164};
// c (0..50) -> path, and index i within path's (2l1+1)
__constant__ int cC2P[51] = {0, 1,1,1, 2,2,2,2,2, 3, 4,4,4, 5,5,5, 6,6,6,
                             7,7,7,7,7, 8,8,8,8,8, 9, 10,10,10,10,10,
                             11,11,11, 12,12,12, 13,13,13,13,13, 14,14,14,14,14};
__constant__ int cC2I[51] = {0, 0,1,2, 0,1,2,3,4, 0, 0,1,2, 0,1,2, 0,1,2,
                             0,1,2,3,4, 0,1,2,3,4, 0, 0,1,2,3,4,
                             0,1,2, 0,1,2, 0,1,2,3,4, 0,1,2,3,4};

// ws layout (floats):
//   [0,1512)      wq a<8 rows (8 floats/row, 189 rows)
//   [1512,1701)   wq a=8
//   [2048, ...)   Mq[4096][144*9] c-major
#define WS_B8   0
#define WS_B1   1512
#define WS_MQ   2048
#define MQ_STRIDE 1296

// ---------------------------------------------------------------------------
// double-precision Wigner machinery
// ---------------------------------------------------------------------------
__device__ __forceinline__ double dfact(int n){
  double r = 1.0;
  for (int i = 2; i <= n; ++i) r *= (double)i;
  return r;
}

__device__ double su2_cg(int j1,int m1,int j2,int m2,int j3,int m3){
  if (m3 != m1 + m2) return 0.0;
  int vmin = -j1 + j2 + m3;
  if (-j1 + m1 > vmin) vmin = -j1 + m1;
  if (0 > vmin) vmin = 0;
  int vmax = j2 + j3 + m1;
  if (j3 - j1 + j2 < vmax) vmax = j3 - j1 + j2;
  if (j3 + m3 < vmax) vmax = j3 + m3;
  double C = sqrt((2.0*j3+1.0)*dfact(j3+j1-j2)*dfact(j3-j1+j2)*dfact(j1+j2-j3)
                  *dfact(j3+m3)*dfact(j3-m3)
                  /(dfact(j1+j2+j3+1)*dfact(j1-m1)*dfact(j1+m1)*dfact(j2-m2)*dfact(j2+m2)));
  double S = 0.0;
  for (int v = vmin; v <= vmax; ++v){
    double term = dfact(j2+j3+m1-v)*dfact(j1-m1+v)
                /(dfact(v)*dfact(j3-j1+j2-v)*dfact(j3+m3-v)*dfact(v+j1-j2-m3));
    S += ((v + j2 + m2) & 1) ? -term : term;
  }
  return C * S;
}

__device__ __forceinline__ void build_q(int l, double qre[5][5], double qim[5][5]){
  for (int r = 0; r < 5; ++r)
    for (int c = 0; c < 5; ++c){ qre[r][c] = 0.0; qim[r][c] = 0.0; }
  double s = 1.0 / sqrt(2.0);
  for (int m = -l; m < 0; ++m){
    qre[l+m][l-m] = s;
    qim[l+m][l+m] = -s;
  }
  qre[l][l] = 1.0;
  for (int m = 1; m <= l; ++m){
    double sgn = (m & 1) ? -1.0 : 1.0;
    qre[l+m][l+m] = sgn * s;
    qim[l+m][l-m] = sgn * s;
  }
  if (l == 1){           // * (-i)
    for (int r = 0; r < 5; ++r)
      for (int c = 0; c < 5; ++c){
        double a = qre[r][c], b = qim[r][c];
        qre[r][c] = b; qim[r][c] = -a;
      }
  } else if (l == 2){    // * (-1)
    for (int r = 0; r < 5; ++r)
      for (int c = 0; c < 5; ++c){ qre[r][c] = -qre[r][c]; qim[r][c] = -qim[r][c]; }
  }
}

// ---------------------------------------------------------------------------
// merged init: one block, 1024 threads. CG (1875-par) -> Cr (615-par) ->
// norms (15 lanes) -> QCART (81-par) -> wq (3375-par) -> ws.
// ---------------------------------------------------------------------------
__global__ __launch_bounds__(1024) void init_kernel(float* __restrict__ ws){
  __shared__ double sQre[3][5][5];
  __shared__ double sQim[3][5][5];
  __shared__ double sCG[NPATH * 125];   // 15000 B
  __shared__ double sCr[615];           //  4920 B
  __shared__ double sInv[NPATH];
  __shared__ double sQCd[81];
  const int tid = threadIdx.x;

  if (tid < 3) build_q(tid, sQre[tid], sQim[tid]);

  for (int t = tid; t < NPATH * 125; t += 1024){
    int p = t / 125, idx = t - p * 125;
    int i = idx / 25, k = (idx / 5) % 5, m = idx % 5;
    int l1 = cP_L1[p], l2 = cP_L2[p], l3 = cP_LO[p];
    double val = 0.0;
    if (i < 2*l1+1 && k < 2*l2+1 && m < 2*l3+1)
      val = su2_cg(l1, i - l1, l2, k - l2, l3, m - l3);
    sCG[t] = val;
  }
  __syncthreads();

  for (int t = tid; t < NPATH * 125; t += 1024){
    int p = t / 125, e = t - p * 125;
    int l1 = cP_L1[p], l2 = cP_L2[p], l3 = cP_LO[p];
    int d1 = 2*l1+1, d2 = 2*l2+1, d3 = 2*l3+1;
    if (e >= d1 * d2 * d3) continue;
    int j = e / (d2 * d3);
    int rem = e - j * (d2 * d3);
    int l = rem / d3, n = rem - l * d3;
    double acc = 0.0;
    for (int i = 0; i < d1; ++i)
      for (int k = 0; k < d2; ++k)
        for (int m = 0; m < d3; ++m){
          double c = sCG[p * 125 + (i*5 + k)*5 + m];
          if (c == 0.0) continue;
          double are = sQre[l1][i][j], aim = sQim[l1][i][j];
          double bre = sQre[l2][k][l], bim = sQim[l2][k][l];
          double tre = are*bre - aim*bim;
          double tim = are*bim + aim*bre;
          double cre = sQre[l3][m][n], cim = sQim[l3][m][n];
          acc += (tre*cre + tim*cim) * c;
        }
    sCr[cP_WOFF[p] + e] = acc;
  }
  __syncthreads();

  if (tid < NPATH){
    int p = tid;
    int sz = (2*cP_L1[p]+1) * (2*cP_L2[p]+1) * (2*cP_LO[p]+1);
    int off = cP_WOFF[p];
    double s2 = 0.0;
    for (int e = 0; e < sz; ++e){ double v = sCr[off+e]; s2 += v*v; }
    sInv[p] = 1.0 / sqrt(s2);
  }
  __syncthreads();

  if (tid < 81){
    int lm = tid / 9, r = tid - lm * 9;
    int l = (lm == 0) ? 0 : ((lm < 4) ? 1 : 2);
    int m = lm - l * l;
    int pq = (l == 0) ? 1 : ((l == 1) ? 5 : 11);
    sQCd[lm * 9 + r] = sCr[cP_WOFF[pq] + r * (2*l + 1) + m] * sInv[pq] * sqrt(2.0*l + 1.0);
  }
  __syncthreads();

  const double AL0 = 0.03608439182435161;   // 1/sqrt(768)
  const double AL1 = 0.04419417382415922;   // sqrt(3/1536)
  const double AL2 = 0.05705443310009863;   // sqrt(5/1536)
  for (int t = tid; t < NPATH * 225; t += 1024){
    int p = t / 225, idx = t - p * 225;
    int i = idx / 45, j = (idx / 9) % 5, a = idx % 9;
    int d1 = 2*cP_L1[p]+1, d2 = 2*cP_L2[p]+1, d3 = 2*cP_LO[p]+1;
    if (i >= d1 || j >= d2) continue;
    int lo = cP_LO[p];
    double al = (lo == 0) ? AL0 : ((lo == 1) ? AL1 : AL2);
    double acc = 0.0;
    for (int m = 0; m < d3; ++m)
      acc += sCr[cP_WOFF[p] + (i*d2 + j)*d3 + m] * sInv[p] * sQCd[(lo*lo + m)*9 + a];
    int row = cP_PROW[p] + i*d2 + j;
    float val = (float)(al * acc);
    if (a < 8) ws[WS_B8 + row*8 + a] = val;
    else       ws[WS_B1 + row]       = val;
  }
}

// ---------------------------------------------------------------------------
// ACCP: one path's contribution to acc[9]
// ---------------------------------------------------------------------------
#define ACCP(TOFF_, PROW_, D1_)                                              \
  { _Pragma("unroll")                                                        \
    for (int i = 0; i < (D1_); ++i){                                         \
      float tv = pT[((TOFF_) + i) * 16 + v];                                 \
      int row = (PROW_) + i * D2 + j;                                        \
      const float4 m0 = *(const float4*)&sB8[row * 8];                       \
      const float4 m1 = *(const float4*)&sB8[row * 8 + 4];                   \
      const float  m8 = sB1[row];                                            \
      acc[0] += tv*m0.x; acc[1] += tv*m0.y; acc[2] += tv*m0.z;               \
      acc[3] += tv*m0.w; acc[4] += tv*m1.x; acc[5] += tv*m1.y;               \
      acc[6] += tv*m1.z; acc[7] += tv*m1.w; acc[8] += tv*m8;                 \
    } }

// ---------------------------------------------------------------------------
// mq_kernel: 256 thr = 4 waves; wave computes Mq (c-major [c][a]) for one
// row-block and stores it contiguously to global ws.
// ---------------------------------------------------------------------------
__global__ __launch_bounds__(256, 4) void mq_kernel(
    const float* __restrict__ feats,    // (4096, 144)
    const int*   __restrict__ layout,   // (E, 2)
    const float* __restrict__ tpw,      // (15, 16, 16)
    const float* __restrict__ ws,       // wq split 8+1
    float*       __restrict__ mqg)      // (4096, 1296) Mq c-major
{
  __shared__ __align__(16) float sB8[189 * 8];      // 6048 B
  __shared__ float sB1[192];                        //  768 B
  __shared__ __align__(16) float sT[4][816];        // 13056 B
  __shared__ __align__(16) float sMq[4][1296];      // 20736 B -> 40.6KB total
  const int tid  = threadIdx.x;
  const int wave = tid >> 6;
  const int lane = tid & 63;

  for (int o = tid; o < 1512; o += 256) sB8[o] = ws[WS_B8 + o];
  if (tid < 189) sB1[tid] = ws[WS_B1 + tid];

  const int rw = blockIdx.x * 4 + wave;     // row-block id
  int rowNode = layout[2 * (rw * 64)];
  rowNode = __builtin_amdgcn_readfirstlane(rowNode);
  const float* __restrict__ x1 = feats + (size_t)rowNode * 144;

  // Phase A: t[k][v]
  float* __restrict__ pT = sT[wave];
  {
    const int v  = lane & 15;
    const int cq = lane >> 4;
    for (int it = 0; it < 13; ++it){
      int c = cq + it * 4;
      if (c < 51){
        int p = cC2P[c], i = cC2I[c];
        int l1 = cP_L1[p];
        int st = 2*l1 + 1;
        int loff = (l1 == 0) ? 0 : ((l1 == 1) ? 16 : 64);
        const float* xb = x1 + loff + i;
        const float* wb = tpw + p * 256 + v;
        float s = 0.f;
        #pragma unroll
        for (int u = 0; u < 16; ++u) s += xb[u * st] * wb[u * 16];
        pT[c * 16 + v] = s;
      }
    }
  }

  __syncthreads();   // sB8/sB1 staged; Phase A done

  // Phase B: Mq[c][a], c-major
  float* __restrict__ pM = sMq[wave];
  for (int rnd = 0; rnd < 3; ++rnd){
    int c = lane + rnd * 64;
    if (c >= 144) break;
    float acc[9];
    #pragma unroll
    for (int a = 0; a < 9; ++a) acc[a] = 0.f;
    if (c < 16){                    // l2 = 0 : paths 0,4,10
      const int v = c, j = 0;
      const int D2 = 1;
      ACCP(0,  0,   1)
      ACCP(10, 38,  3)
      ACCP(30, 110, 5)
    } else if (c < 64){             // l2 = 1 : paths 1,3,5,7,11,13
      const int v = (c - 16) / 3, j = (c - 16) % 3;
      const int D2 = 3;
      ACCP(1,  1,   3)
      ACCP(9,  35,  1)
      ACCP(13, 41,  3)
      ACCP(19, 65,  5)
      ACCP(35, 115, 3)
      ACCP(41, 139, 5)
    } else {                        // l2 = 2 : paths 2,6,8,9,12,14
      const int v = (c - 64) / 5, j = (c - 64) % 5;
      const int D2 = 5;
      ACCP(4,  10,  5)
      ACCP(16, 50,  3)
      ACCP(24, 80,  5)
      ACCP(29, 105, 1)
      ACCP(38, 124, 3)
      ACCP(46, 164, 5)
    }
    #pragma unroll
    for (int a = 0; a < 9; ++a) pM[c * 9 + a] = acc[a];
  }
  // wave-local LDS order: compiler's lgkmcnt before the reads below suffices

  // store Mq contiguously (coalesced b128)
  float* __restrict__ dst = mqg + (size_t)rw * MQ_STRIDE;
  #pragma unroll
  for (int r = 0; r < 6; ++r){
    int idx = lane + r * 64;                 // float4 index 0..323
    if (idx < 324){
      float4 vv = *(const float4*)(pM + idx * 4);
      *(float4*)(dst + idx * 4) = vv;
    }
  }
}

// ---------------------------------------------------------------------------
// cart_kernel: 256 thr = 4 waves, wave per row-block. Mq pointer forced
// uniform via readfirstlane -> s_load (SGPR operands). Grid 1024 == mq grid
// -> same block->XCD round-robin -> Mq read from writer XCD's L2.
// ---------------------------------------------------------------------------
__global__ __launch_bounds__(256) void cart_kernel(
    const float* __restrict__ feats,
    const int*   __restrict__ layout,
    const float* __restrict__ mqg,      // (4096, 1296) Mq c-major
    float*       __restrict__ out)
{
  __shared__ __align__(16) float sOut[4][576];
  const int tid  = threadIdx.x;
  const int wave = tid >> 6;
  const int lane = tid & 63;
  const int rw = __builtin_amdgcn_readfirstlane(blockIdx.x * 4 + wave);

  const float* __restrict__ m = mqg + (size_t)rw * MQ_STRIDE;  // SGPR-based
  const size_t e = (size_t)rw * 64 + lane;
  const int col = layout[2 * e + 1];
  const float* __restrict__ x2 = feats + (size_t)col * 144;

  float acc[9];
  #pragma unroll
  for (int a = 0; a < 9; ++a) acc[a] = 0.f;

  for (int cc = 0; cc < 36; ++cc){
    const float4 xv = *(const float4*)(x2 + cc * 4);
    const float* mb = m + cc * 36;      // 36 contiguous uniform dwords
    #pragma unroll
    for (int q4 = 0; q4 < 4; ++q4){
      const float xq = (q4 == 0) ? xv.x : (q4 == 1) ? xv.y : (q4 == 2) ? xv.z : xv.w;
      #pragma unroll
      for (int a = 0; a < 9; ++a) acc[a] += xq * mb[q4 * 9 + a];
    }
  }

  // coalesced store via LDS staging (wave-local, no barrier needed)
  float* __restrict__ pO = sOut[wave];
  #pragma unroll
  for (int a = 0; a < 9; ++a) pO[lane * 9 + a] = acc[a];
  float* __restrict__ ob = out + (size_t)rw * 576;
  #pragma unroll
  for (int r = 0; r < 3; ++r){
    int idx = lane + r * 64;                 // float4 index 0..143
    if (idx < 144){
      float4 vv = *(const float4*)(pO + idx * 4);
      *(float4*)(ob + idx * 4) = vv;
    }
  }
}

// ---------------------------------------------------------------------------
// fallback: fused kernel (used only if ws is too small for Mq)
// ---------------------------------------------------------------------------
__global__ __launch_bounds__(256, 4) void fused_kernel(
    const float* __restrict__ feats,
    const int*   __restrict__ layout,
    const float* __restrict__ tpw,
    const float* __restrict__ ws,
    float*       __restrict__ out)
{
  __shared__ __align__(16) float sB8[189 * 8];
  __shared__ float sB1[192];
  __shared__ __align__(16) float sT[4][816];
  __shared__ __align__(16) float sMqT[4][1296];
  const int tid  = threadIdx.x;
  const int wave = tid >> 6;
  const int lane = tid & 63;

  for (int o = tid; o < 1512; o += 256) sB8[o] = ws[WS_B8 + o];
  if (tid < 189) sB1[tid] = ws[WS_B1 + tid];

  const int rw = blockIdx.x * 4 + wave;
  const int e0 = rw * 64;
  int rowNode = layout[2 * e0];
  rowNode = __builtin_amdgcn_readfirstlane(rowNode);
  const float* __restrict__ x1 = feats + (size_t)rowNode * 144;

  float* __restrict__ pT = sT[wave];
  {
    const int v  = lane & 15;
    const int cq = lane >> 4;
    for (int it = 0; it < 13; ++it){
      int c = cq + it * 4;
      if (c < 51){
        int p = cC2P[c], i = cC2I[c];
        int l1 = cP_L1[p];
        int st = 2*l1 + 1;
        int loff = (l1 == 0) ? 0 : ((l1 == 1) ? 16 : 64);
        const float* xb = x1 + loff + i;
        const float* wb = tpw + p * 256 + v;
        float s = 0.f;
        #pragma unroll
        for (int u = 0; u < 16; ++u) s += xb[u * st] * wb[u * 16];
        pT[c * 16 + v] = s;
      }
    }
  }
  __syncthreads();

  float* __restrict__ pM = sMqT[wave];
  for (int rnd = 0; rnd < 3; ++rnd){
    int c = lane + rnd * 64;
    if (c >= 144) break;
    float acc[9];
    #pragma unroll
    for (int a = 0; a < 9; ++a) acc[a] = 0.f;
    if (c < 16){
      const int v = c, j = 0;
      const int D2 = 1;
      ACCP(0,  0,   1)
      ACCP(10, 38,  3)
      ACCP(30, 110, 5)
    } else if (c < 64){
      const int v = (c - 16) / 3, j = (c - 16) % 3;
      const int D2 = 3;
      ACCP(1,  1,   3)
      ACCP(9,  35,  1)
      ACCP(13, 41,  3)
      ACCP(19, 65,  5)
      ACCP(35, 115, 3)
      ACCP(41, 139, 5)
    } else {
      const int v = (c - 64) / 5, j = (c - 64) % 5;
      const int D2 = 5;
      ACCP(4,  10,  5)
      ACCP(16, 50,  3)
      ACCP(24, 80,  5)
      ACCP(29, 105, 1)
      ACCP(38, 124, 3)
      ACCP(46, 164, 5)
    }
    #pragma unroll
    for (int a = 0; a < 9; ++a) pM[a * 144 + c] = acc[a];
  }

  const size_t e = (size_t)e0 + lane;
  const int col = layout[2 * e + 1];
  const float* __restrict__ x2 = feats + (size_t)col * 144;

  float acc[9];
  #pragma unroll
  for (int a = 0; a < 9; ++a) acc[a] = 0.f;

  for (int cc = 0; cc < 36; ++cc){
    const float4 x = *(const float4*)(x2 + cc * 4);
    const float* mb = pM + cc * 4;
    #pragma unroll
    for (int a = 0; a < 9; ++a){
      float4 mv = *(const float4*)(mb + a * 144);
      acc[a] += x.x*mv.x + x.y*mv.y + x.z*mv.z + x.w*mv.w;
    }
  }

  #pragma unroll
  for (int a = 0; a < 9; ++a) pT[lane * 9 + a] = acc[a];
  float* ob = out + (size_t)e0 * 9;
  #pragma unroll
  for (int r = 0; r < 3; ++r){
    int idx = lane + r * 64;
    if (idx < 144){
      float4 vv = *(const float4*)(pT + idx * 4);
      *(float4*)(ob + idx * 4) = vv;
    }
  }
}

// ---------------------------------------------------------------------------
// sym_tiled: 16x16 cell tile-pairs through LDS; fully coalesced; each element
// read+written exactly once. Block = (config b, tile-pair tp), 256 threads.
// ---------------------------------------------------------------------------
__global__ __launch_bounds__(256) void sym_tiled(float* __restrict__ out){
  __shared__ float sA[16 * 145];
  __shared__ float sB[16 * 145];
  const int tid = threadIdx.x;
  const int b  = blockIdx.x / 10;
  const int tp = blockIdx.x - b * 10;
  const int TI[10] = {0,0,0,0,1,1,1,2,2,3};
  const int TJ[10] = {0,1,2,3,1,2,3,2,3,3};
  const int ti = TI[tp], tj = TJ[tp];
  const bool diag = (ti == tj);
  const size_t cfgBase = (size_t)b * 4096 * 9;

  for (int idx = tid; idx < 2304; idx += 256){
    int r = idx / 144, off = idx - r * 144;
    sA[r * 145 + off] = out[cfgBase + ((size_t)(ti*16 + r) * 64 + tj*16) * 9 + off];
  }
  if (!diag){
    for (int idx = tid; idx < 2304; idx += 256){
      int r = idx / 144, off = idx - r * 144;
      sB[r * 145 + off] = out[cfgBase + ((size_t)(tj*16 + r) * 64 + ti*16) * 9 + off];
    }
  }
  __syncthreads();

  const int di = tid >> 4, dj = tid & 15;
  const float* A = sA;
  const float* B = diag ? sA : sB;
  float oa[9], ob[9];
  #pragma unroll
  for (int a = 0; a < 3; ++a)
    #pragma unroll
    for (int d = 0; d < 3; ++d){
      oa[a*3+d] = 0.5f * (A[di*145 + dj*9 + a*3+d] + B[dj*145 + di*9 + d*3+a]);
      if (!diag)
        ob[a*3+d] = 0.5f * (B[di*145 + dj*9 + a*3+d] + A[dj*145 + di*9 + d*3+a]);
    }
  __syncthreads();

  #pragma unroll
  for (int r9 = 0; r9 < 9; ++r9) sA[di*145 + dj*9 + r9] = oa[r9];
  if (!diag){
    #pragma unroll
    for (int r9 = 0; r9 < 9; ++r9) sB[di*145 + dj*9 + r9] = ob[r9];
  }
  __syncthreads();

  for (int idx = tid; idx < 2304; idx += 256){
    int r = idx / 144, off = idx - r * 144;
    out[cfgBase + ((size_t)(ti*16 + r) * 64 + tj*16) * 9 + off] = sA[r * 145 + off];
  }
  if (!diag){
    for (int idx = tid; idx < 2304; idx += 256){
      int r = idx / 144, off = idx - r * 144;
      out[cfgBase + ((size_t)(tj*16 + r) * 64 + ti*16) * 9 + off] = sB[r * 145 + off];
    }
  }
}

// ---------------------------------------------------------------------------
extern "C" void kernel_launch(void* const* d_in, const int* in_sizes, int n_in,
                              void* d_out, int out_size, void* d_ws, size_t ws_size,
                              hipStream_t stream) {
  const float* feats  = (const float*)d_in[0];   // (4096, 144)
  const int*   layout = (const int*)  d_in[1];   // (E, 2)
  const float* tpw    = (const float*)d_in[2];   // (15, 16, 16)
  float* out = (float*)d_out;
  float* ws  = (float*)d_ws;

  const int E = in_sizes[1] / 2;                 // 262144
  const int R = E / 64;                          // 4096 row-blocks
  const int B = E / 4096;                        // 64 configs

  init_kernel<<<1, 1024, 0, stream>>>(ws);

  const size_t need = ((size_t)WS_MQ + (size_t)R * MQ_STRIDE) * sizeof(float);
  if (ws_size >= need){
    float* mqg = ws + WS_MQ;
    mq_kernel  <<<R / 4, 256, 0, stream>>>(feats, layout, tpw, ws, mqg);
    cart_kernel<<<R / 4, 256, 0, stream>>>(feats, layout, mqg, out);
  } else {
    fused_kernel<<<R / 4, 256, 0, stream>>>(feats, layout, tpw, ws, out);
  }
  sym_tiled<<<B * 10, 256, 0, stream>>>(out);
}

// Round 8
// 124.308 us; speedup vs baseline: 1.1782x; 1.1782x over previous
//
#include <hip/hip_runtime.h>
#include <math.h>

// ---------------------------------------------------------------------------
// IrrepsToHessian, round 8.
//
// R7 post-mortem: dur_us carries a ~45-50us harness floor (256MiB ws 0xAA
// poison fill at 42us is stream-ordered inside each iteration). Our
// controllable part ~95us. Sinks: runtime init of compile-time constants,
// and cart's strided x2 gather (64 line-txns per instr).
//
// R8: (1) Wigner-3j/QCART/alpha computed at COMPILE TIME via constexpr
// (Newton csqrt, constexpr CG; one constexpr object per path to stay under
// clang's constexpr step budget) -> __constant__ wq table, init kernel
// deleted. (2) cart: 4 row-blocks/block share one config's 64 columns ->
// X2 staged TRANSPOSED into LDS once (coalesced, pad 65 -> conflict-free),
// Mq via readfirstlane-uniform pointer -> s_load SGPR-operand FMAs.
// ---------------------------------------------------------------------------

#define NPATH 15

// ======================= compile-time Wigner machinery =====================
constexpr double cfact(int n){ double r = 1.0; for (int i = 2; i <= n; ++i) r *= (double)i; return r; }
constexpr double csqrt(double x){
  if (x <= 0.0) return 0.0;
  double g = x < 1.0 ? 1.0 : x;
  for (int i = 0; i < 64; ++i) g = 0.5*(g + x/g);
  return g;
}

constexpr double ccg(int j1,int m1,int j2,int m2,int j3,int m3){
  if (m3 != m1 + m2) return 0.0;
  int vmin = -j1 + j2 + m3;
  if (-j1 + m1 > vmin) vmin = -j1 + m1;
  if (0 > vmin) vmin = 0;
  int vmax = j2 + j3 + m1;
  if (j3 - j1 + j2 < vmax) vmax = j3 - j1 + j2;
  if (j3 + m3 < vmax) vmax = j3 + m3;
  double C = csqrt((2.0*j3+1.0)*cfact(j3+j1-j2)*cfact(j3-j1+j2)*cfact(j1+j2-j3)
                   *cfact(j3+m3)*cfact(j3-m3)
                   /(cfact(j1+j2+j3+1)*cfact(j1-m1)*cfact(j1+m1)*cfact(j2-m2)*cfact(j2+m2)));
  double S = 0.0;
  for (int v = vmin; v <= vmax; ++v){
    double term = cfact(j2+j3+m1-v)*cfact(j1-m1+v)
                /(cfact(v)*cfact(j3-j1+j2-v)*cfact(j3+m3-v)*cfact(v+j1-j2-m3));
    S += ((v + j2 + m2) & 1) ? -term : term;
  }
  return C * S;
}

struct QM { double re[5][5]; double im[5][5]; };
constexpr QM cbuild_q(int l){
  QM q{};
  double s = 1.0 / csqrt(2.0);
  for (int m = -l; m < 0; ++m){
    q.re[l+m][l-m] = s;
    q.im[l+m][l+m] = -s;
  }
  q.re[l][l] = 1.0;
  for (int m = 1; m <= l; ++m){
    double sg = (m & 1) ? -1.0 : 1.0;
    q.re[l+m][l+m] = sg * s;
    q.im[l+m][l-m] = sg * s;
  }
  if (l == 1){           // * (-i): (a+bi) -> (b, -a)
    for (int r = 0; r < 5; ++r)
      for (int c = 0; c < 5; ++c){
        double a = q.re[r][c], b = q.im[r][c];
        q.re[r][c] = b; q.im[r][c] = -a;
      }
  } else if (l == 2){    // * (-1)
    for (int r = 0; r < 5; ++r)
      for (int c = 0; c < 5; ++c){ q.re[r][c] = -q.re[r][c]; q.im[r][c] = -q.im[r][c]; }
  }
  return q;
}

struct CRP { double v[125]; };   // normalized real w3j, [(i*d2+j)*d3+m]
constexpr CRP make_cr(int l1, int l2, int l3){
  QM q1 = cbuild_q(l1), q2 = cbuild_q(l2), q3 = cbuild_q(l3);
  const int d1 = 2*l1+1, d2 = 2*l2+1, d3 = 2*l3+1;
  double CG[125] = {};
  for (int i = 0; i < d1; ++i)
    for (int k = 0; k < d2; ++k)
      for (int m = 0; m < d3; ++m)
        CG[(i*5 + k)*5 + m] = ccg(l1, i-l1, l2, k-l2, l3, m-l3);
  CRP o{};
  for (int j = 0; j < d1; ++j)
    for (int l = 0; l < d2; ++l)
      for (int n = 0; n < d3; ++n){
        double acc = 0.0;
        for (int i = 0; i < d1; ++i)
          for (int k = 0; k < d2; ++k)
            for (int m = 0; m < d3; ++m){
              double c = CG[(i*5 + k)*5 + m];
              if (c == 0.0) continue;
              double are = q1.re[i][j], aim = q1.im[i][j];
              double bre = q2.re[k][l], bim = q2.im[k][l];
              double tre = are*bre - aim*bim;
              double tim = are*bim + aim*bre;
              double cre = q3.re[m][n], cim = q3.im[m][n];
              acc += (tre*cre + tim*cim) * c;   // Re( q1 q2 conj(q3) CG )
            }
        o.v[(j*d2 + l)*d3 + n] = acc;
      }
  double s2 = 0.0;
  for (int e = 0; e < d1*d2*d3; ++e) s2 += o.v[e]*o.v[e];
  double inv = 1.0 / csqrt(s2);
  for (int e = 0; e < d1*d2*d3; ++e) o.v[e] *= inv;
  return o;
}

// one constexpr variable per path -> each evaluation has its own step budget
constexpr CRP CR0  = make_cr(0,0,0);
constexpr CRP CR1  = make_cr(1,1,0);
constexpr CRP CR2  = make_cr(2,2,0);
constexpr CRP CR3  = make_cr(0,1,1);
constexpr CRP CR4  = make_cr(1,0,1);
constexpr CRP CR5  = make_cr(1,1,1);
constexpr CRP CR6  = make_cr(1,2,1);
constexpr CRP CR7  = make_cr(2,1,1);
constexpr CRP CR8  = make_cr(2,2,1);
constexpr CRP CR9  = make_cr(0,2,2);
constexpr CRP CR10 = make_cr(2,0,2);
constexpr CRP CR11 = make_cr(1,1,2);
constexpr CRP CR12 = make_cr(1,2,2);
constexpr CRP CR13 = make_cr(2,1,2);
constexpr CRP CR14 = make_cr(2,2,2);

struct QCT { double v[81]; };    // QCART[lm][i*3+j]
constexpr QCT make_qc(){
  QCT q{};
  for (int lm = 0; lm < 9; ++lm){
    int l = (lm == 0) ? 0 : ((lm < 4) ? 1 : 2);
    int m = lm - l*l;
    const CRP& cr = (l == 0) ? CR1 : ((l == 1) ? CR5 : CR11);  // paths (1,1,l)
    double sc = csqrt(2.0*l + 1.0);
    for (int r = 0; r < 9; ++r)
      q.v[lm*9 + r] = cr.v[r*(2*l+1) + m] * sc;
  }
  return q;
}
constexpr QCT QCt = make_qc();

// wq layout (as before): 189 rows, split b8 (a<8) + b1 (a==8)
struct WQT { float b8[189*8]; float b1[189]; };
constexpr WQT make_wq(){
  WQT t{};
  const CRP* crs[NPATH] = {&CR0,&CR1,&CR2,&CR3,&CR4,&CR5,&CR6,&CR7,&CR8,&CR9,
                           &CR10,&CR11,&CR12,&CR13,&CR14};
  const int L1[NPATH]   = {0,1,2,0,1,1,1,2,2,0,2,1,1,2,2};
  const int L2[NPATH]   = {0,1,2,1,0,1,2,1,2,2,0,1,2,1,2};
  const int LO[NPATH]   = {0,0,0,1,1,1,1,1,1,2,2,2,2,2,2};
  const int PROW[NPATH] = {0,1,10,35,38,41,50,65,80,105,110,115,124,139,164};
  const double AL[3] = { csqrt(1.0/768.0), csqrt(3.0/1536.0), csqrt(5.0/1536.0) };
  for (int p = 0; p < NPATH; ++p){
    const int d1 = 2*L1[p]+1, d2 = 2*L2[p]+1, d3 = 2*LO[p]+1, lo = LO[p];
    for (int i = 0; i < d1; ++i)
      for (int j = 0; j < d2; ++j)
        for (int a = 0; a < 9; ++a){
          double acc = 0.0;
          for (int m = 0; m < d3; ++m)
            acc += crs[p]->v[(i*d2 + j)*d3 + m] * QCt.v[(lo*lo + m)*9 + a];
          double val = AL[lo] * acc;
          int row = PROW[p] + i*d2 + j;
          if (a < 8) t.b8[row*8 + a] = (float)val;
          else       t.b1[row]       = (float)val;
        }
  }
  return t;
}
__constant__ WQT cWQ = make_wq();

// ======================= runtime tables (mq Phase A/B) =====================
__constant__ int cP_L1[NPATH]   = {0,1,2,0,1,1,1,2,2,0,2,1,1,2,2};
__constant__ int cC2P[51] = {0, 1,1,1, 2,2,2,2,2, 3, 4,4,4, 5,5,5, 6,6,6,
                             7,7,7,7,7, 8,8,8,8,8, 9, 10,10,10,10,10,
                             11,11,11, 12,12,12, 13,13,13,13,13, 14,14,14,14,14};
__constant__ int cC2I[51] = {0, 0,1,2, 0,1,2,3,4, 0, 0,1,2, 0,1,2, 0,1,2,
                             0,1,2,3,4, 0,1,2,3,4, 0, 0,1,2,3,4,
                             0,1,2, 0,1,2, 0,1,2,3,4, 0,1,2,3,4};

#define MQ_STRIDE 1296

// ACCP: one path's contribution to acc[9]
#define ACCP(TOFF_, PROW_, D1_)                                              \
  { _Pragma("unroll")                                                        \
    for (int i = 0; i < (D1_); ++i){                                         \
      float tv = pT[((TOFF_) + i) * 16 + v];                                 \
      int row = (PROW_) + i * D2 + j;                                        \
      const float4 m0 = *(const float4*)&sB8[row * 8];                       \
      const float4 m1 = *(const float4*)&sB8[row * 8 + 4];                   \
      const float  m8 = sB1[row];                                            \
      acc[0] += tv*m0.x; acc[1] += tv*m0.y; acc[2] += tv*m0.z;               \
      acc[3] += tv*m0.w; acc[4] += tv*m1.x; acc[5] += tv*m1.y;               \
      acc[6] += tv*m1.z; acc[7] += tv*m1.w; acc[8] += tv*m8;                 \
    } }

// ---------------------------------------------------------------------------
// mq_kernel: 256 thr = 4 waves; wave computes Mq (c-major [c][a]) for one
// row-block and stores it contiguously to global ws.
// ---------------------------------------------------------------------------
__global__ __launch_bounds__(256, 4) void mq_kernel(
    const float* __restrict__ feats,    // (4096, 144)
    const int*   __restrict__ layout,   // (E, 2)
    const float* __restrict__ tpw,      // (15, 16, 16)
    float*       __restrict__ mqg)      // (4096, 1296) Mq c-major
{
  __shared__ __align__(16) float sB8[189 * 8];      // 6048 B
  __shared__ float sB1[192];                        //  768 B
  __shared__ __align__(16) float sT[4][816];        // 13056 B
  __shared__ __align__(16) float sMq[4][1296];      // 20736 B -> 40.6KB total
  const int tid  = threadIdx.x;
  const int wave = tid >> 6;
  const int lane = tid & 63;

  for (int o = tid; o < 1512; o += 256) sB8[o] = cWQ.b8[o];
  if (tid < 189) sB1[tid] = cWQ.b1[tid];

  const int rw = blockIdx.x * 4 + wave;     // row-block id
  int rowNode = layout[2 * (rw * 64)];
  rowNode = __builtin_amdgcn_readfirstlane(rowNode);
  const float* __restrict__ x1 = feats + (size_t)rowNode * 144;

  // Phase A: t[k][v]
  float* __restrict__ pT = sT[wave];
  {
    const int v  = lane & 15;
    const int cq = lane >> 4;
    for (int it = 0; it < 13; ++it){
      int c = cq + it * 4;
      if (c < 51){
        int p = cC2P[c], i = cC2I[c];
        int l1 = cP_L1[p];
        int st = 2*l1 + 1;
        int loff = (l1 == 0) ? 0 : ((l1 == 1) ? 16 : 64);
        const float* xb = x1 + loff + i;
        const float* wb = tpw + p * 256 + v;
        float s = 0.f;
        #pragma unroll
        for (int u = 0; u < 16; ++u) s += xb[u * st] * wb[u * 16];
        pT[c * 16 + v] = s;
      }
    }
  }

  __syncthreads();   // sB8/sB1 staged; Phase A done

  // Phase B: Mq[c][a], c-major
  float* __restrict__ pM = sMq[wave];
  for (int rnd = 0; rnd < 3; ++rnd){
    int c = lane + rnd * 64;
    if (c >= 144) break;
    float acc[9];
    #pragma unroll
    for (int a = 0; a < 9; ++a) acc[a] = 0.f;
    if (c < 16){                    // l2 = 0 : paths 0,4,10
      const int v = c, j = 0;
      const int D2 = 1;
      ACCP(0,  0,   1)
      ACCP(10, 38,  3)
      ACCP(30, 110, 5)
    } else if (c < 64){             // l2 = 1 : paths 1,3,5,7,11,13
      const int v = (c - 16) / 3, j = (c - 16) % 3;
      const int D2 = 3;
      ACCP(1,  1,   3)
      ACCP(9,  35,  1)
      ACCP(13, 41,  3)
      ACCP(19, 65,  5)
      ACCP(35, 115, 3)
      ACCP(41, 139, 5)
    } else {                        // l2 = 2 : paths 2,6,8,9,12,14
      const int v = (c - 64) / 5, j = (c - 64) % 5;
      const int D2 = 5;
      ACCP(4,  10,  5)
      ACCP(16, 50,  3)
      ACCP(24, 80,  5)
      ACCP(29, 105, 1)
      ACCP(38, 124, 3)
      ACCP(46, 164, 5)
    }
    #pragma unroll
    for (int a = 0; a < 9; ++a) pM[c * 9 + a] = acc[a];
  }
  // wave-local LDS order: compiler's lgkmcnt before the reads below suffices

  // store Mq contiguously (coalesced b128)
  float* __restrict__ dst = mqg + (size_t)rw * MQ_STRIDE;
  #pragma unroll
  for (int r = 0; r < 6; ++r){
    int idx = lane + r * 64;                 // float4 index 0..323
    if (idx < 324){
      float4 vv = *(const float4*)(pM + idx * 4);
      *(float4*)(dst + idx * 4) = vv;
    }
  }
}

// ---------------------------------------------------------------------------
// cart_kernel: block = 4 row-blocks of ONE config (share the 64 columns).
// X2 staged transposed in LDS (pad 65 -> conflict-free b32 reads); Mq via
// readfirstlane-uniform pointer -> s_load SGPR-operand v_fmac.
// ---------------------------------------------------------------------------
__global__ __launch_bounds__(256) void cart_kernel(
    const float* __restrict__ feats,
    const int*   __restrict__ layout,
    const float* __restrict__ mqg,      // (4096, 1296) Mq c-major
    float*       __restrict__ out)
{
  __shared__ float sX2T[144 * 65];               // 37440 B
  __shared__ int   sCol[64];
  __shared__ __align__(16) float sOut[4][576];   //  9216 B -> 46.9KB total
  const int tid  = threadIdx.x;
  const int wave = tid >> 6;
  const int lane = tid & 63;
  const int rwBase = blockIdx.x * 4;             // 4 row-blocks, same config

  if (tid < 64) sCol[tid] = layout[2 * ((size_t)rwBase * 64 + tid) + 1];
  __syncthreads();

  // stage X2 transposed: sX2T[c][j] = feats[col_j][c]
  #pragma unroll
  for (int k = 0; k < 9; ++k){
    int q = k * 256 + tid;                       // 0..2303 float4 tasks
    int j = q / 36, c4 = q - j * 36;
    const float4 xv = *(const float4*)(feats + (size_t)sCol[j] * 144 + c4 * 4);
    int c0 = c4 * 4;
    sX2T[(c0+0)*65 + j] = xv.x;
    sX2T[(c0+1)*65 + j] = xv.y;
    sX2T[(c0+2)*65 + j] = xv.z;
    sX2T[(c0+3)*65 + j] = xv.w;
  }
  __syncthreads();

  const int rw = __builtin_amdgcn_readfirstlane(rwBase + wave);
  const float* __restrict__ mq = mqg + (size_t)rw * MQ_STRIDE;  // SGPR-based

  float acc[9];
  #pragma unroll
  for (int a = 0; a < 9; ++a) acc[a] = 0.f;

  #pragma unroll 8
  for (int c = 0; c < 144; ++c){
    float x = sX2T[c * 65 + lane];
    #pragma unroll
    for (int a = 0; a < 9; ++a) acc[a] += x * mq[c * 9 + a];
  }

  // coalesced store via LDS staging (wave-local, no barrier needed)
  float* __restrict__ pO = sOut[wave];
  #pragma unroll
  for (int a = 0; a < 9; ++a) pO[lane * 9 + a] = acc[a];
  float* __restrict__ ob = out + (size_t)rw * 576;
  #pragma unroll
  for (int r = 0; r < 3; ++r){
    int idx = lane + r * 64;                 // float4 index 0..143
    if (idx < 144){
      float4 vv = *(const float4*)(pO + idx * 4);
      *(float4*)(ob + idx * 4) = vv;
    }
  }
}

// ---------------------------------------------------------------------------
// fallback: fused kernel (used only if ws is too small for Mq)
// ---------------------------------------------------------------------------
__global__ __launch_bounds__(256, 4) void fused_kernel(
    const float* __restrict__ feats,
    const int*   __restrict__ layout,
    const float* __restrict__ tpw,
    float*       __restrict__ out)
{
  __shared__ __align__(16) float sB8[189 * 8];
  __shared__ float sB1[192];
  __shared__ __align__(16) float sT[4][816];
  __shared__ __align__(16) float sMqT[4][1296];
  const int tid  = threadIdx.x;
  const int wave = tid >> 6;
  const int lane = tid & 63;

  for (int o = tid; o < 1512; o += 256) sB8[o] = cWQ.b8[o];
  if (tid < 189) sB1[tid] = cWQ.b1[tid];

  const int rw = blockIdx.x * 4 + wave;
  const int e0 = rw * 64;
  int rowNode = layout[2 * e0];
  rowNode = __builtin_amdgcn_readfirstlane(rowNode);
  const float* __restrict__ x1 = feats + (size_t)rowNode * 144;

  float* __restrict__ pT = sT[wave];
  {
    const int v  = lane & 15;
    const int cq = lane >> 4;
    for (int it = 0; it < 13; ++it){
      int c = cq + it * 4;
      if (c < 51){
        int p = cC2P[c], i = cC2I[c];
        int l1 = cP_L1[p];
        int st = 2*l1 + 1;
        int loff = (l1 == 0) ? 0 : ((l1 == 1) ? 16 : 64);
        const float* xb = x1 + loff + i;
        const float* wb = tpw + p * 256 + v;
        float s = 0.f;
        #pragma unroll
        for (int u = 0; u < 16; ++u) s += xb[u * st] * wb[u * 16];
        pT[c * 16 + v] = s;
      }
    }
  }
  __syncthreads();

  float* __restrict__ pM = sMqT[wave];
  for (int rnd = 0; rnd < 3; ++rnd){
    int c = lane + rnd * 64;
    if (c >= 144) break;
    float acc[9];
    #pragma unroll
    for (int a = 0; a < 9; ++a) acc[a] = 0.f;
    if (c < 16){
      const int v = c, j = 0;
      const int D2 = 1;
      ACCP(0,  0,   1)
      ACCP(10, 38,  3)
      ACCP(30, 110, 5)
    } else if (c < 64){
      const int v = (c - 16) / 3, j = (c - 16) % 3;
      const int D2 = 3;
      ACCP(1,  1,   3)
      ACCP(9,  35,  1)
      ACCP(13, 41,  3)
      ACCP(19, 65,  5)
      ACCP(35, 115, 3)
      ACCP(41, 139, 5)
    } else {
      const int v = (c - 64) / 5, j = (c - 64) % 5;
      const int D2 = 5;
      ACCP(4,  10,  5)
      ACCP(16, 50,  3)
      ACCP(24, 80,  5)
      ACCP(29, 105, 1)
      ACCP(38, 124, 3)
      ACCP(46, 164, 5)
    }
    #pragma unroll
    for (int a = 0; a < 9; ++a) pM[a * 144 + c] = acc[a];
  }

  const size_t e = (size_t)e0 + lane;
  const int col = layout[2 * e + 1];
  const float* __restrict__ x2 = feats + (size_t)col * 144;

  float acc[9];
  #pragma unroll
  for (int a = 0; a < 9; ++a) acc[a] = 0.f;

  for (int cc = 0; cc < 36; ++cc){
    const float4 x = *(const float4*)(x2 + cc * 4);
    const float* mb = pM + cc * 4;
    #pragma unroll
    for (int a = 0; a < 9; ++a){
      float4 mv = *(const float4*)(mb + a * 144);
      acc[a] += x.x*mv.x + x.y*mv.y + x.z*mv.z + x.w*mv.w;
    }
  }

  #pragma unroll
  for (int a = 0; a < 9; ++a) pT[lane * 9 + a] = acc[a];
  float* ob = out + (size_t)e0 * 9;
  #pragma unroll
  for (int r = 0; r < 3; ++r){
    int idx = lane + r * 64;
    if (idx < 144){
      float4 vv = *(const float4*)(pT + idx * 4);
      *(float4*)(ob + idx * 4) = vv;
    }
  }
}

// ---------------------------------------------------------------------------
// sym_tiled: 16x16 cell tile-pairs through LDS; fully coalesced; each element
// read+written exactly once. Block = (config b, tile-pair tp), 256 threads.
// ---------------------------------------------------------------------------
__global__ __launch_bounds__(256) void sym_tiled(float* __restrict__ out){
  __shared__ float sA[16 * 145];
  __shared__ float sB[16 * 145];
  const int tid = threadIdx.x;
  const int b  = blockIdx.x / 10;
  const int tp = blockIdx.x - b * 10;
  const int TI[10] = {0,0,0,0,1,1,1,2,2,3};
  const int TJ[10] = {0,1,2,3,1,2,3,2,3,3};
  const int ti = TI[tp], tj = TJ[tp];
  const bool diag = (ti == tj);
  const size_t cfgBase = (size_t)b * 4096 * 9;

  for (int idx = tid; idx < 2304; idx += 256){
    int r = idx / 144, off = idx - r * 144;
    sA[r * 145 + off] = out[cfgBase + ((size_t)(ti*16 + r) * 64 + tj*16) * 9 + off];
  }
  if (!diag){
    for (int idx = tid; idx < 2304; idx += 256){
      int r = idx / 144, off = idx - r * 144;
      sB[r * 145 + off] = out[cfgBase + ((size_t)(tj*16 + r) * 64 + ti*16) * 9 + off];
    }
  }
  __syncthreads();

  const int di = tid >> 4, dj = tid & 15;
  const float* A = sA;
  const float* B = diag ? sA : sB;
  float oa[9], ob[9];
  #pragma unroll
  for (int a = 0; a < 3; ++a)
    #pragma unroll
    for (int d = 0; d < 3; ++d){
      oa[a*3+d] = 0.5f * (A[di*145 + dj*9 + a*3+d] + B[dj*145 + di*9 + d*3+a]);
      if (!diag)
        ob[a*3+d] = 0.5f * (B[di*145 + dj*9 + a*3+d] + A[dj*145 + di*9 + d*3+a]);
    }
  __syncthreads();

  #pragma unroll
  for (int r9 = 0; r9 < 9; ++r9) sA[di*145 + dj*9 + r9] = oa[r9];
  if (!diag){
    #pragma unroll
    for (int r9 = 0; r9 < 9; ++r9) sB[di*145 + dj*9 + r9] = ob[r9];
  }
  __syncthreads();

  for (int idx = tid; idx < 2304; idx += 256){
    int r = idx / 144, off = idx - r * 144;
    out[cfgBase + ((size_t)(ti*16 + r) * 64 + tj*16) * 9 + off] = sA[r * 145 + off];
  }
  if (!diag){
    for (int idx = tid; idx < 2304; idx += 256){
      int r = idx / 144, off = idx - r * 144;
      out[cfgBase + ((size_t)(tj*16 + r) * 64 + ti*16) * 9 + off] = sB[r * 145 + off];
    }
  }
}

// ---------------------------------------------------------------------------
extern "C" void kernel_launch(void* const* d_in, const int* in_sizes, int n_in,
                              void* d_out, int out_size, void* d_ws, size_t ws_size,
                              hipStream_t stream) {
  const float* feats  = (const float*)d_in[0];   // (4096, 144)
  const int*   layout = (const int*)  d_in[1];   // (E, 2)
  const float* tpw    = (const float*)d_in[2];   // (15, 16, 16)
  float* out = (float*)d_out;
  float* ws  = (float*)d_ws;

  const int E = in_sizes[1] / 2;                 // 262144
  const int R = E / 64;                          // 4096 row-blocks
  const int B = E / 4096;                        // 64 configs

  const size_t need = (size_t)R * MQ_STRIDE * sizeof(float);
  if (ws_size >= need){
    float* mqg = ws;
    mq_kernel  <<<R / 4, 256, 0, stream>>>(feats, layout, tpw, mqg);
    cart_kernel<<<R / 4, 256, 0, stream>>>(feats, layout, mqg, out);
  } else {
    fused_kernel<<<R / 4, 256, 0, stream>>>(feats, layout, tpw, out);
  }
  sym_tiled<<<B * 10, 256, 0, stream>>>(out);
}